// Round 16
// baseline (56.450 us; speedup 1.0000x reference)
//
#include <hip/hip_runtime.h>
#include <hip/hip_fp16.h>

typedef _Float16 half8 __attribute__((ext_vector_type(8)));
typedef float f32x4 __attribute__((ext_vector_type(4)));

#define CIN   128
#define COUT  128
#define HH    32
#define WW    32
#define LTOT  1024
#define KKT   9
#define KDIM  1152

// LDS: B tile 6 rows x 32 cols x 256B = 48KB at [0, 49152).
// After the loop, [0,69632) reused as the K-split reduction buffer.
#define SMEM_BYTES 69632

// ---- prep: fragment-ordered weights ----
// wt3[q*1024 + o*8 + j] = f16(w[(o*128 + c)*9 + kk]),  q = kk*16 + (c>>3), j = c&7.
__global__ void prep_w_kernel(const float* __restrict__ w, _Float16* __restrict__ wt) {
  int i = blockIdx.x * 256 + threadIdx.x;   // 576 blocks cover 147456
  int q = i >> 10;
  int o = (i >> 3) & 127;
  int j = i & 7;
  int kk = q >> 4;
  int c  = ((q & 15) << 3) + j;
  wt[i] = (_Float16)w[(o * CIN + c) * KKT + kk];
}

// r12 kernel (best: 25.0 us total). 256 blocks x 512 threads, block tile
// 128o x 128l, K-split waves, barrier-free 18-site loop, A direct
// global->VGPR, B resident LDS, mask folded via v_pk_mul_f16.
__global__ __launch_bounds__(512, 2)
void conv_mfma_kernel(const float* __restrict__ x,
                      const _Float16* __restrict__ wt,
                      const float* __restrict__ mask,
                      const float* __restrict__ bias,
                      float* __restrict__ out) {
  extern __shared__ char smem[];
  const int tid = threadIdx.x;
  int bid = blockIdx.x;
  bid = (bid & 7) * 32 + (bid >> 3);     // XCD swizzle, bijective (256 % 8 == 0)
  const int b  = bid >> 3;
  const int l0 = (bid & 7) << 7;         // 128 l per block
  const int h0 = (bid & 7) << 2;         // 4 h-rows per block

  const int lane = tid & 63, wid = tid >> 6;
  const int lr = lane & 15, lg = lane >> 4;
  const int kh = wid >> 2;               // K-half: 0 -> c 0..63, 1 -> c 64..127
  const int wq = wid & 3;
  const int mw = (wq >> 1) << 6;         // wave m base {0,64}
  const int nw = (wq & 1) << 6;          // wave n base {0,64}

  // ---- mask preload: 36 scalars per lane (kk x nj) ----
  float mv[9][4];
  {
    const float* mr = mask + l0 + nw + lr;
#pragma unroll
    for (int kk = 0; kk < 9; ++kk)
#pragma unroll
      for (int nj = 0; nj < 4; ++nj)
        mv[kk][nj] = mr[kk * LTOT + nj * 16];
  }

  // ---- B-build: x[b][c][hg][w] -> fp16 tile, single pass (512 threads) ----
  const int wv = tid & 31, q16 = tid >> 5;         // col (w), 16-B chunk 0..15
  char* bdst = smem + wv * 256 + ((q16 ^ (wv & 15)) << 4);
  const float* xb = x + (size_t)b * CIN * LTOT;
  {
    float fr[6][8];
#pragma unroll
    for (int r = 0; r < 6; ++r) {
      const int hg = h0 - 1 + r;
      if ((unsigned)hg < (unsigned)HH) {           // block-uniform branch
        const float* s = xb + (size_t)q16 * 8 * LTOT + hg * WW + wv;
#pragma unroll
        for (int j = 0; j < 8; ++j) fr[r][j] = s[(size_t)j * LTOT];
      }
    }
    asm volatile("s_waitcnt vmcnt(0)" ::: "memory");
#pragma unroll
    for (int r = 0; r < 6; ++r) {
      const int hg = h0 - 1 + r;
      half8 v = (half8){0, 0, 0, 0, 0, 0, 0, 0};
      if ((unsigned)hg < (unsigned)HH) {
#pragma unroll
        for (int j = 0; j < 8; ++j) v[j] = (_Float16)fr[r][j];
      }
      *(half8*)(bdst + r * 8192) = v;
    }
  }
#pragma unroll
  for (int kk = 0; kk < 9; ++kk)
#pragma unroll
    for (int nj = 0; nj < 4; ++nj)
      asm volatile("" : "+v"(mv[kk][nj]));         // keep masks resident past drain
  __syncthreads();                                 // B tile visible to all waves

  const char* abase = (const char*)wt + lg * 2048 + (mw + lr) * 16;

  f32x4 acc[4][4];                                 // [mi][nj], 64 VGPR
#pragma unroll
  for (int mi = 0; mi < 4; ++mi)
#pragma unroll
    for (int nj = 0; nj < 4; ++nj)
      acc[mi][nj] = (f32x4){0.f, 0.f, 0.f, 0.f};

  // ---- barrier-free 9-tap loop ----
#pragma unroll
  for (int kk = 0; kk < 9; ++kk) {
    const int di = (kk * 11) >> 5;               // kk/3
    const int dj = kk - 3 * di;

    const char* Bp[4];
    int xk[4];
    _Float16 mh[4];
#pragma unroll
    for (int nj = 0; nj < 4; ++nj) {
      const int wb = ((nj & 1) << 4) + lr + dj - 1;
      const bool vld = (unsigned)wb < (unsigned)WW;
      const int wc = vld ? wb : 0;
      const int hrow = (nw >> 5) + (nj >> 1) + di;   // 0..5
      Bp[nj] = smem + hrow * 8192 + wc * 256;
      xk[nj] = wc & 15;
      mh[nj] = (_Float16)(vld ? mv[kk][nj] : 0.f);
    }

    __builtin_amdgcn_s_setprio(1);
#pragma unroll
    for (int s = 0; s < 2; ++s) {
      const int qb = kk * 16 + (kh * 2 + s) * 4;
      const char* ab = abase + qb * 2048;
      const int q = qb + lg;
      half8 a0 = *(const half8*)(ab);
      half8 a1 = *(const half8*)(ab + 256);
      half8 a2 = *(const half8*)(ab + 512);
      half8 a3 = *(const half8*)(ab + 768);
      half8 b0 = *(const half8*)(Bp[0] + (((q & 15) ^ xk[0]) << 4)) * mh[0];
      half8 b1 = *(const half8*)(Bp[1] + (((q & 15) ^ xk[1]) << 4)) * mh[1];
      half8 b2 = *(const half8*)(Bp[2] + (((q & 15) ^ xk[2]) << 4)) * mh[2];
      half8 b3 = *(const half8*)(Bp[3] + (((q & 15) ^ xk[3]) << 4)) * mh[3];
      acc[0][0] = __builtin_amdgcn_mfma_f32_16x16x32_f16(a0, b0, acc[0][0], 0, 0, 0);
      acc[1][0] = __builtin_amdgcn_mfma_f32_16x16x32_f16(a1, b0, acc[1][0], 0, 0, 0);
      acc[2][0] = __builtin_amdgcn_mfma_f32_16x16x32_f16(a2, b0, acc[2][0], 0, 0, 0);
      acc[3][0] = __builtin_amdgcn_mfma_f32_16x16x32_f16(a3, b0, acc[3][0], 0, 0, 0);
      acc[0][1] = __builtin_amdgcn_mfma_f32_16x16x32_f16(a0, b1, acc[0][1], 0, 0, 0);
      acc[1][1] = __builtin_amdgcn_mfma_f32_16x16x32_f16(a1, b1, acc[1][1], 0, 0, 0);
      acc[2][1] = __builtin_amdgcn_mfma_f32_16x16x32_f16(a2, b1, acc[2][1], 0, 0, 0);
      acc[3][1] = __builtin_amdgcn_mfma_f32_16x16x32_f16(a3, b1, acc[3][1], 0, 0, 0);
      acc[0][2] = __builtin_amdgcn_mfma_f32_16x16x32_f16(a0, b2, acc[0][2], 0, 0, 0);
      acc[1][2] = __builtin_amdgcn_mfma_f32_16x16x32_f16(a1, b2, acc[1][2], 0, 0, 0);
      acc[2][2] = __builtin_amdgcn_mfma_f32_16x16x32_f16(a2, b2, acc[2][2], 0, 0, 0);
      acc[3][2] = __builtin_amdgcn_mfma_f32_16x16x32_f16(a3, b2, acc[3][2], 0, 0, 0);
      acc[0][3] = __builtin_amdgcn_mfma_f32_16x16x32_f16(a0, b3, acc[0][3], 0, 0, 0);
      acc[1][3] = __builtin_amdgcn_mfma_f32_16x16x32_f16(a1, b3, acc[1][3], 0, 0, 0);
      acc[2][3] = __builtin_amdgcn_mfma_f32_16x16x32_f16(a2, b3, acc[2][3], 0, 0, 0);
      acc[3][3] = __builtin_amdgcn_mfma_f32_16x16x32_f16(a3, b3, acc[3][3], 0, 0, 0);
    }
    __builtin_amdgcn_s_setprio(0);
  }

  // ---- K-split reduction through LDS ----
  __syncthreads();
  char* red = smem + wq * 17408 + lane * 272;
  if (kh == 1) {
#pragma unroll
    for (int mi = 0; mi < 4; ++mi)
#pragma unroll
      for (int nj = 0; nj < 4; ++nj)
        *(f32x4*)(red + (mi * 4 + nj) * 16) = acc[mi][nj];
  }
  __syncthreads();

  if (kh == 0) {
#pragma unroll
    for (int mi = 0; mi < 4; ++mi)
#pragma unroll
      for (int nj = 0; nj < 4; ++nj) {
        f32x4 p = *(const f32x4*)(red + (mi * 4 + nj) * 16);
        acc[mi][nj].x += p.x; acc[mi][nj].y += p.y;
        acc[mi][nj].z += p.z; acc[mi][nj].w += p.w;
      }

    float* outb = out + (size_t)b * COUT * LTOT + l0;
#pragma unroll
    for (int mi = 0; mi < 4; ++mi) {
#pragma unroll
      for (int rr = 0; rr < 4; ++rr) {
        const int o = mw + mi * 16 + lg * 4 + rr;
        const float bv = bias[o];
        float* orow = outb + (size_t)o * LTOT + nw + lr;
#pragma unroll
        for (int nj = 0; nj < 4; ++nj)
          orow[nj * 16] = acc[mi][nj][rr] + bv;
      }
    }
  }
}

extern "C" void kernel_launch(void* const* d_in, const int* in_sizes, int n_in,
                              void* d_out, int out_size, void* d_ws, size_t ws_size,
                              hipStream_t stream) {
  const float* x    = (const float*)d_in[0];
  const float* mask = (const float*)d_in[1];
  const float* w    = (const float*)d_in[2];
  const float* bias = (const float*)d_in[3];
  float* out = (float*)d_out;
  _Float16* wt = (_Float16*)d_ws;

  (void)hipFuncSetAttribute(reinterpret_cast<const void*>(conv_mfma_kernel),
                            hipFuncAttributeMaxDynamicSharedMemorySize, SMEM_BYTES);

  prep_w_kernel<<<576, 256, 0, stream>>>(w, wt);
  // CALIBRATION ROUND: conv launched 3x (idempotent). All graph replays are
  // warm, so total = fixed + 3*conv_warm; conv_warm = (total - 25.0)/2.
  conv_mfma_kernel<<<256, 512, SMEM_BYTES, stream>>>(x, wt, mask, bias, out);
  conv_mfma_kernel<<<256, 512, SMEM_BYTES, stream>>>(x, wt, mask, bias, out);
  conv_mfma_kernel<<<256, 512, SMEM_BYTES, stream>>>(x, wt, mask, bias, out);
}

// Round 17
// 25.795 us; speedup vs baseline: 2.1884x; 2.1884x over previous
//
#include <hip/hip_runtime.h>
#include <hip/hip_fp16.h>

typedef _Float16 half8 __attribute__((ext_vector_type(8)));
typedef _Float16 half4 __attribute__((ext_vector_type(4)));
typedef float f32x4 __attribute__((ext_vector_type(4)));

#define CIN   128
#define COUT  128
#define HH    32
#define WW    32
#define LTOT  1024
#define KKT   9
#define KDIM  1152

// LDS: B tile 6 rows x 32 cols x 256B = 48KB at [0, 49152).
// After the loop, [0,65536) reused as the bidirectional reduction buffer.
#define SMEM_BYTES 69632

// ---- prep: fragment-ordered weights ----
// wt3[q*1024 + o*8 + j] = f16(w[(o*128 + c)*9 + kk]),  q = kk*16 + (c>>3), j = c&7.
__global__ void prep_w_kernel(const float* __restrict__ w, _Float16* __restrict__ wt) {
  int i = blockIdx.x * 256 + threadIdx.x;   // 576 blocks cover 147456
  int q = i >> 10;
  int o = (i >> 3) & 127;
  int j = i & 7;
  int kk = q >> 4;
  int c  = ((q & 15) << 3) + j;
  wt[i] = (_Float16)w[(o * CIN + c) * KKT + kk];
}

// 256 blocks x 512 threads (8 waves, 2/SIMD). Block tile 128o x 128l.
// K-split waves (kh) x 2m x 2n, wave tile 64o x 64l, mfma 16x16x32 f16.
// Barrier-free K-loop; A direct global->VGPR with pre-drain prefetch of the
// first two sites + rotating depth-1 reload; B resident LDS, mask folded into
// B-fragments (v_pk_mul_f16); bidirectional split reduction/epilogue.
__global__ __launch_bounds__(512, 2)
void conv_mfma_kernel(const float* __restrict__ x,
                      const _Float16* __restrict__ wt,
                      const float* __restrict__ mask,
                      const float* __restrict__ bias,
                      float* __restrict__ out) {
  extern __shared__ char smem[];
  const int tid = threadIdx.x;
  int bid = blockIdx.x;
  bid = (bid & 7) * 32 + (bid >> 3);     // XCD swizzle, bijective (256 % 8 == 0)
  const int b  = bid >> 3;
  const int l0 = (bid & 7) << 7;         // 128 l per block
  const int h0 = (bid & 7) << 2;         // 4 h-rows per block

  const int lane = tid & 63, wid = tid >> 6;
  const int lr = lane & 15, lg = lane >> 4;
  const int kh = wid >> 2;               // K-half: 0 -> c 0..63, 1 -> c 64..127
  const int wq = wid & 3;
  const int mw = (wq >> 1) << 6;         // wave m base {0,64}
  const int nw = (wq & 1) << 6;          // wave n base {0,64}

  // ---- mask preload, packed f16 (18 VGPRs) ----
  half4 mvh[9];
  {
    const float* mr = mask + l0 + nw + lr;
#pragma unroll
    for (int kk = 0; kk < 9; ++kk)
#pragma unroll
      for (int nj = 0; nj < 4; ++nj)
        mvh[kk][nj] = (_Float16)mr[kk * LTOT + nj * 16];
  }

  // ---- B-build: issue x loads ----
  const int wv = tid & 31, q16 = tid >> 5;         // col (w), 16-B chunk 0..15
  char* bdst = smem + wv * 256 + ((q16 ^ (wv & 15)) << 4);
  const float* xb = x + (size_t)b * CIN * LTOT;
  float fr[6][8];
#pragma unroll
  for (int r = 0; r < 6; ++r) {
    const int hg = h0 - 1 + r;
    if ((unsigned)hg < (unsigned)HH) {             // block-uniform branch
      const float* s = xb + (size_t)q16 * 8 * LTOT + hg * WW + wv;
#pragma unroll
      for (int j = 0; j < 8; ++j) fr[r][j] = s[(size_t)j * LTOT];
    }
  }

  // ---- pre-drain A prefetch: sites 0 (even) and 1 (odd) of tap 0 ----
  // byte addr(q, o) = q*2048 + o*16; q = qb + lg; qbE(kk)=kk*16+kh*8, qbO=+4.
  const char* abase = (const char*)wt + lg * 2048 + (mw + lr) * 16;
  const char* abE = abase + (kh * 8) * 2048;
  const char* abO = abase + (kh * 8 + 4) * 2048;
  half8 aE0 = *(const half8*)(abE);
  half8 aE1 = *(const half8*)(abE + 256);
  half8 aE2 = *(const half8*)(abE + 512);
  half8 aE3 = *(const half8*)(abE + 768);
  half8 aO0 = *(const half8*)(abO);
  half8 aO1 = *(const half8*)(abO + 256);
  half8 aO2 = *(const half8*)(abO + 512);
  half8 aO3 = *(const half8*)(abO + 768);

  asm volatile("s_waitcnt vmcnt(0)" ::: "memory");
  // pin prefetched values + masks so their loads cannot sink past the drain
  asm volatile("" : "+v"(aE0), "+v"(aE1), "+v"(aE2), "+v"(aE3));
  asm volatile("" : "+v"(aO0), "+v"(aO1), "+v"(aO2), "+v"(aO3));
#pragma unroll
  for (int kk = 0; kk < 9; ++kk) asm volatile("" : "+v"(mvh[kk]));

  // ---- convert + write B tile (zero OOB rows) ----
#pragma unroll
  for (int r = 0; r < 6; ++r) {
    const int hg = h0 - 1 + r;
    half8 v = (half8){0, 0, 0, 0, 0, 0, 0, 0};
    if ((unsigned)hg < (unsigned)HH) {
#pragma unroll
      for (int j = 0; j < 8; ++j) v[j] = (_Float16)fr[r][j];
    }
    *(half8*)(bdst + r * 8192) = v;
  }
  __syncthreads();                                 // B tile visible to all waves

  // tap-invariant B chunk indices: q15E = kh*8+lg, q15O = kh*8+4+lg
  const int cE = kh * 8 + lg;
  const int cO = cE + 4;

  f32x4 acc[4][4];                                 // [mi][nj], 64 VGPR
#pragma unroll
  for (int mi = 0; mi < 4; ++mi)
#pragma unroll
    for (int nj = 0; nj < 4; ++nj)
      acc[mi][nj] = (f32x4){0.f, 0.f, 0.f, 0.f};

  // ---- barrier-free 9-tap loop, rotating depth-1 A reload ----
#pragma unroll
  for (int kk = 0; kk < 9; ++kk) {
    const int di = (kk * 11) >> 5;               // kk/3
    const int dj = kk - 3 * di;

    const char* Bp[4];
    int xk[4];
    _Float16 mh[4];
#pragma unroll
    for (int nj = 0; nj < 4; ++nj) {
      const int wb = ((nj & 1) << 4) + lr + dj - 1;
      const bool vld = (unsigned)wb < (unsigned)WW;
      const int wc = vld ? wb : 0;
      const int hrow = (nw >> 5) + (nj >> 1) + di;   // 0..5
      Bp[nj] = smem + hrow * 8192 + wc * 256;
      xk[nj] = wc & 15;
      mh[nj] = vld ? mvh[kk][nj] : (_Float16)0.f;
    }

    // ---- site even (uses aE*, then reloads aE* for tap kk+1) ----
    {
      half8 b0 = *(const half8*)(Bp[0] + ((cE ^ xk[0]) << 4)) * mh[0];
      half8 b1 = *(const half8*)(Bp[1] + ((cE ^ xk[1]) << 4)) * mh[1];
      half8 b2 = *(const half8*)(Bp[2] + ((cE ^ xk[2]) << 4)) * mh[2];
      half8 b3 = *(const half8*)(Bp[3] + ((cE ^ xk[3]) << 4)) * mh[3];
      __builtin_amdgcn_s_setprio(1);
      acc[0][0] = __builtin_amdgcn_mfma_f32_16x16x32_f16(aE0, b0, acc[0][0], 0, 0, 0);
      acc[1][0] = __builtin_amdgcn_mfma_f32_16x16x32_f16(aE1, b0, acc[1][0], 0, 0, 0);
      acc[2][0] = __builtin_amdgcn_mfma_f32_16x16x32_f16(aE2, b0, acc[2][0], 0, 0, 0);
      acc[3][0] = __builtin_amdgcn_mfma_f32_16x16x32_f16(aE3, b0, acc[3][0], 0, 0, 0);
      acc[0][1] = __builtin_amdgcn_mfma_f32_16x16x32_f16(aE0, b1, acc[0][1], 0, 0, 0);
      acc[1][1] = __builtin_amdgcn_mfma_f32_16x16x32_f16(aE1, b1, acc[1][1], 0, 0, 0);
      acc[2][1] = __builtin_amdgcn_mfma_f32_16x16x32_f16(aE2, b1, acc[2][1], 0, 0, 0);
      acc[3][1] = __builtin_amdgcn_mfma_f32_16x16x32_f16(aE3, b1, acc[3][1], 0, 0, 0);
      acc[0][2] = __builtin_amdgcn_mfma_f32_16x16x32_f16(aE0, b2, acc[0][2], 0, 0, 0);
      acc[1][2] = __builtin_amdgcn_mfma_f32_16x16x32_f16(aE1, b2, acc[1][2], 0, 0, 0);
      acc[2][2] = __builtin_amdgcn_mfma_f32_16x16x32_f16(aE2, b2, acc[2][2], 0, 0, 0);
      acc[3][2] = __builtin_amdgcn_mfma_f32_16x16x32_f16(aE3, b2, acc[3][2], 0, 0, 0);
      acc[0][3] = __builtin_amdgcn_mfma_f32_16x16x32_f16(aE0, b3, acc[0][3], 0, 0, 0);
      acc[1][3] = __builtin_amdgcn_mfma_f32_16x16x32_f16(aE1, b3, acc[1][3], 0, 0, 0);
      acc[2][3] = __builtin_amdgcn_mfma_f32_16x16x32_f16(aE2, b3, acc[2][3], 0, 0, 0);
      acc[3][3] = __builtin_amdgcn_mfma_f32_16x16x32_f16(aE3, b3, acc[3][3], 0, 0, 0);
      __builtin_amdgcn_s_setprio(0);
      if (kk < 8) {                               // reload E for next tap
        const char* ne = abase + ((kk + 1) * 16 + kh * 8) * 2048;
        aE0 = *(const half8*)(ne);
        aE1 = *(const half8*)(ne + 256);
        aE2 = *(const half8*)(ne + 512);
        aE3 = *(const half8*)(ne + 768);
      }
    }

    // ---- site odd (uses aO*, then reloads aO* for tap kk+1) ----
    {
      half8 b0 = *(const half8*)(Bp[0] + ((cO ^ xk[0]) << 4)) * mh[0];
      half8 b1 = *(const half8*)(Bp[1] + ((cO ^ xk[1]) << 4)) * mh[1];
      half8 b2 = *(const half8*)(Bp[2] + ((cO ^ xk[2]) << 4)) * mh[2];
      half8 b3 = *(const half8*)(Bp[3] + ((cO ^ xk[3]) << 4)) * mh[3];
      __builtin_amdgcn_s_setprio(1);
      acc[0][0] = __builtin_amdgcn_mfma_f32_16x16x32_f16(aO0, b0, acc[0][0], 0, 0, 0);
      acc[1][0] = __builtin_amdgcn_mfma_f32_16x16x32_f16(aO1, b0, acc[1][0], 0, 0, 0);
      acc[2][0] = __builtin_amdgcn_mfma_f32_16x16x32_f16(aO2, b0, acc[2][0], 0, 0, 0);
      acc[3][0] = __builtin_amdgcn_mfma_f32_16x16x32_f16(aO3, b0, acc[3][0], 0, 0, 0);
      acc[0][1] = __builtin_amdgcn_mfma_f32_16x16x32_f16(aO0, b1, acc[0][1], 0, 0, 0);
      acc[1][1] = __builtin_amdgcn_mfma_f32_16x16x32_f16(aO1, b1, acc[1][1], 0, 0, 0);
      acc[2][1] = __builtin_amdgcn_mfma_f32_16x16x32_f16(aO2, b1, acc[2][1], 0, 0, 0);
      acc[3][1] = __builtin_amdgcn_mfma_f32_16x16x32_f16(aO3, b1, acc[3][1], 0, 0, 0);
      acc[0][2] = __builtin_amdgcn_mfma_f32_16x16x32_f16(aO0, b2, acc[0][2], 0, 0, 0);
      acc[1][2] = __builtin_amdgcn_mfma_f32_16x16x32_f16(aO1, b2, acc[1][2], 0, 0, 0);
      acc[2][2] = __builtin_amdgcn_mfma_f32_16x16x32_f16(aO2, b2, acc[2][2], 0, 0, 0);
      acc[3][2] = __builtin_amdgcn_mfma_f32_16x16x32_f16(aO3, b2, acc[3][2], 0, 0, 0);
      acc[0][3] = __builtin_amdgcn_mfma_f32_16x16x32_f16(aO0, b3, acc[0][3], 0, 0, 0);
      acc[1][3] = __builtin_amdgcn_mfma_f32_16x16x32_f16(aO1, b3, acc[1][3], 0, 0, 0);
      acc[2][3] = __builtin_amdgcn_mfma_f32_16x16x32_f16(aO2, b3, acc[2][3], 0, 0, 0);
      acc[3][3] = __builtin_amdgcn_mfma_f32_16x16x32_f16(aO3, b3, acc[3][3], 0, 0, 0);
      __builtin_amdgcn_s_setprio(0);
      if (kk < 8) {                               // reload O for next tap
        const char* no_ = abase + ((kk + 1) * 16 + kh * 8 + 4) * 2048;
        aO0 = *(const half8*)(no_);
        aO1 = *(const half8*)(no_ + 256);
        aO2 = *(const half8*)(no_ + 512);
        aO3 = *(const half8*)(no_ + 768);
      }
    }
  }

  // ---- bidirectional split reduction + epilogue (all 8 waves store) ----
  // kh0 stores mi 0..1 (writes mi 2..3 to LDS); kh1 stores mi 2..3 (writes 0..1).
  __syncthreads();
  {
    char* myred = smem + wid * 8192 + lane * 128;
    const int miW = (kh == 0) ? 2 : 0;             // half I hand over
#pragma unroll
    for (int m2 = 0; m2 < 2; ++m2)
#pragma unroll
      for (int nj = 0; nj < 4; ++nj)
        *(f32x4*)(myred + (m2 * 4 + nj) * 16) = acc[miW + m2][nj];
  }
  __syncthreads();
  {
    const char* pred = smem + (wid ^ 4) * 8192 + lane * 128;
    const int miS = (kh == 0) ? 0 : 2;             // half I store
    float* outb = out + (size_t)b * COUT * LTOT + l0;
#pragma unroll
    for (int m2 = 0; m2 < 2; ++m2) {
      f32x4 sum[4];
#pragma unroll
      for (int nj = 0; nj < 4; ++nj) {
        f32x4 p = *(const f32x4*)(pred + (m2 * 4 + nj) * 16);
        sum[nj].x = acc[miS + m2][nj].x + p.x;
        sum[nj].y = acc[miS + m2][nj].y + p.y;
        sum[nj].z = acc[miS + m2][nj].z + p.z;
        sum[nj].w = acc[miS + m2][nj].w + p.w;
      }
#pragma unroll
      for (int rr = 0; rr < 4; ++rr) {
        const int o = mw + (miS + m2) * 16 + lg * 4 + rr;
        const float bv = bias[o];
        float* orow = outb + (size_t)o * LTOT + nw + lr;
#pragma unroll
        for (int nj = 0; nj < 4; ++nj)
          orow[nj * 16] = sum[nj][rr] + bv;
      }
    }
  }
}

extern "C" void kernel_launch(void* const* d_in, const int* in_sizes, int n_in,
                              void* d_out, int out_size, void* d_ws, size_t ws_size,
                              hipStream_t stream) {
  const float* x    = (const float*)d_in[0];
  const float* mask = (const float*)d_in[1];
  const float* w    = (const float*)d_in[2];
  const float* bias = (const float*)d_in[3];
  float* out = (float*)d_out;
  _Float16* wt = (_Float16*)d_ws;

  (void)hipFuncSetAttribute(reinterpret_cast<const void*>(conv_mfma_kernel),
                            hipFuncAttributeMaxDynamicSharedMemorySize, SMEM_BYTES);

  prep_w_kernel<<<576, 256, 0, stream>>>(w, wt);
  conv_mfma_kernel<<<256, 512, SMEM_BYTES, stream>>>(x, wt, mask, bias, out);
}